// Round 12
// baseline (420.444 us; speedup 1.0000x reference)
//
#include <hip/hip_runtime.h>

// ScoreNetGNN: B=50000 graphs x 7 nodes, fully-connected (42 edges/graph).
// R6: MFMA pipeline (16x16x32 bf16 split hi+lo). R12: truncation-split.
// R13: parallel pack + packed-H. R16: B-frags from L1 + (128,3): occ 31.4%.
// R17: A-frags built from PQ LDS. R19/R24: liveness surgery -> verified best
//   (counter 333+-4us). R20 AGPR park -10%; R21 packed-X neutral; R22
//   in-reg max -11%; R23 setprio -7%. Rules learned: never perturb the MFMA
//   cluster schedule; no serial cross-lane chains; occupancy is hard-capped
//   at 3 waves/SIMD (total reg = 2x arch VGPR, 4/4 configs exact).
// R25 (this): pure DS-op deletion, nothing else.
//   Layer passes fused: per ntc, qq-cluster then pp-cluster, C written
//   DIRECTLY to ROW-indexed PP/QQ planes; pp fixup (p+vb-q) uses the
//   register q -> copyQ/fixP deleted (-70 DS/layer x3). Init pass writes
//   C directly to X planes (-26). ~-236 DS + ~150 VALU per wave, bitwise-
//   identical arithmetic. Plane stride 272B (68dw: 4-row C-write groups
//   2-way = free, R13's H2S rationale). LDS 12928/wave, still 6 blocks/CU.
// f32 I/O hardcoded (R3 counters: WRITE_SIZE = 4 B/elem).

#define NB 50000

typedef unsigned short u16;
typedef unsigned int u32;
typedef short short8 __attribute__((ext_vector_type(8)));
typedef float f32x4 __attribute__((ext_vector_type(4)));
typedef unsigned int u32x4 __attribute__((ext_vector_type(4)));

// d_ws fragment offsets (u16 units). frag stride 1024 u16 (hi 512 | lo 512),
// lane entry = 8 u16 (16B). Total 94208 u16 = 188416 bytes.
#define OFF_I  0
#define OFF_1A 8192
#define OFF_2A 24576
#define OFF_3A 49152
#define OFF_1B 73728
#define OFF_2B 81920
#define OFF_WT 90112
#define OFF_3B 92160

// LDS per-wave geometry (bytes), base W:
//  [0,4352)     PP plane: 16 rows x 64 f32 @ stride 272 (ROW-indexed pp';
//               rows 7,15 junk). X (16 rows x 64 bf16 @ stride 144,
//               hi [0,2304) lo [2304,~4530)) overlays PP+QQ-row0; all uses
//               time-disjoint (X consumed into regs before planes written;
//               planes dead before X rewritten).
//  [4352,8704)  QQ plane: 16 rows x 64 f32 @ stride 272 (ROW-indexed qq).
//  [8704,12928) Sb: f32 C 16 rows @ stride 264 (embed + edgeconv + L3b strip)
#define HSTR 144
#define HLO  2304
#define PQS  272
#define QOFF 4352
#define SOFF 8704
#define SSTR 264
#define WREG 12928

__device__ __forceinline__ float b2f(u16 u) {
    return __uint_as_float(((u32)u) << 16);
}
__device__ __forceinline__ u16 f2b(float f) {
    u32 u = __float_as_uint(f);
    u += 0x7FFFu + ((u >> 16) & 1u);   // RNE
    return (u16)(u >> 16);
}
// split v into bf16 hi (truncated, v-hi exact) + bf16 lo (RNE of residual)
__device__ __forceinline__ void split2(float v, u16& h, u16& l) {
    u32 u = __float_as_uint(v);
    h = (u16)(u >> 16);
    float d = v - __uint_as_float(u & 0xffff0000u);
    l = f2b(d);
}
__device__ __forceinline__ float bcast(float v, int l) {
    return __uint_as_float(__builtin_amdgcn_readlane(__float_as_uint(v), l));
}

// ---- setup: pack weights into split-bf16 MFMA B-fragments ----
// grid (92, 8): blockIdx.y = element j within lane entry; 128 thr = half x lane.
__global__ __launch_bounds__(128) void pack_kernel(
    const float* __restrict__ wi2, const float* __restrict__ w1a,
    const float* __restrict__ w2a, const float* __restrict__ w3a,
    const float* __restrict__ w1b, const float* __restrict__ w2b,
    const float* __restrict__ wt,  const float* __restrict__ w3b,
    u16* __restrict__ ws)
{
    int blk = blockIdx.x;
    int j    = blockIdx.y;
    int half = threadIdx.x >> 6;          // 0 = hi, 1 = lo
    int lane = threadIdx.x & 63;
    float v;
    u16* dst;
    if (blk < 88) {
        const float* src; int NT, qoff, obase, frag;
        if (blk < 8)       { src = wi2; NT = 4; qoff = 0;  obase = OFF_I;  frag = blk;      }
        else if (blk < 24) { src = w1a; NT = 8; qoff = 64; obase = OFF_1A; frag = blk - 8;  }
        else if (blk < 48) { src = w2a; NT = 8; qoff = 96; obase = OFF_2A; frag = blk - 24; }
        else if (blk < 72) { src = w3a; NT = 8; qoff = 96; obase = OFF_3A; frag = blk - 48; }
        else if (blk < 80) { src = w1b; NT = 4; qoff = 0;  obase = OFF_1B; frag = blk - 72; }
        else               { src = w2b; NT = 4; qoff = 0;  obase = OFF_2B; frag = blk - 80; }
        int kt = frag / NT, nt = frag % NT;
        int k = kt * 32 + (lane >> 4) * 8 + j;
        int n = nt * 16 + (lane & 15);
        int idx = (n < 64) ? (k * 64 + n) : ((qoff + k) * 64 + (n - 64));
        v = src[idx];
        dst = ws + obase + frag * 1024 + half * 512 + lane * 8 + j;
    } else if (blk < 90) {               // wt (32,32): 2 n-frags
        int frag = blk - 88;
        int k = (lane >> 4) * 8 + j;
        int n = frag * 16 + (lane & 15);
        v = wt[k * 32 + n];
        dst = ws + OFF_WT + frag * 1024 + half * 512 + lane * 8 + j;
    } else {                             // w3b (64,3): 2 k-frags, cols 3..15 = 0
        int frag = blk - 90;
        int k = frag * 32 + (lane >> 4) * 8 + j;
        int n = lane & 15;
        v = (n < 3) ? w3b[k * 3 + n] : 0.f;
        dst = ws + OFF_3B + frag * 1024 + half * 512 + lane * 8 + j;
    }
    u16 hi = f2b(v);
    *dst = (half == 0) ? hi : f2b(v - b2f(hi));
}

__device__ __forceinline__ f32x4 mfma1(short8 a, short8 b, f32x4 acc) {
    return __builtin_amdgcn_mfma_f32_16x16x32_bf16(a, b, acc, 0, 0, 0);
}
__device__ __forceinline__ f32x4 mfma3(short8 ah, short8 al, short8 bh, short8 bl, f32x4 acc) {
    acc = mfma1(ah, bh, acc);
    acc = mfma1(ah, bl, acc);
    acc = mfma1(al, bh, acc);
    return acc;   // lo*lo dropped
}

// node k (0..13) -> row (g0 rows 0-6, g1 rows 8-14; rows 7,15 junk)
#define ROW(k) ((k) < 7 ? (k) : (k) + 1)

// write one node value (col L) into X planes of region G
__device__ __forceinline__ void putX(char* G, int k, int L, float v) {
    int r = ROW(k);
    u16 h, l;
    split2(v, h, l);
    *(u16*)(G + r * HSTR + L * 2) = h;
    *(u16*)(G + HLO + r * HSTR + L * 2) = l;
}
// A-frags kt 0,1 from G (cols 0-63); kt 2 (xs) is register-resident.
__device__ __forceinline__ void loadA2(const char* G, int L, short8* Ah, short8* Al) {
#pragma unroll
    for (int kt = 0; kt < 2; ++kt) {
        Ah[kt] = *(const short8*)(G + (L & 15) * HSTR + kt * 64 + (L >> 4) * 16);
        Al[kt] = *(const short8*)(G + HLO + (L & 15) * HSTR + kt * 64 + (L >> 4) * 16);
    }
}
// Fused layer pass: for each ntc, qq cluster (f=kt*8+4+ntc) then pp cluster
// (f=kt*8+ntc); C written DIRECTLY to ROW-indexed QQ / PP planes, with the
// pp fixup (p + vb - q) using the register-resident q. Replaces the old
// {lin_pass(qq) -> Sb -> copyQ -> lin_pass(pp) -> Sb -> fixP} round-trip.
template<int KT>
__device__ __forceinline__ void layer_pass(const u16* __restrict__ ws, int off,
                                           const short8* Ah, const short8* Al,
                                           char* PQ, const float* __restrict__ bA,
                                           int L) {
    float vbs[4];
#pragma unroll
    for (int ntc = 0; ntc < 4; ++ntc) vbs[ntc] = bA[ntc * 16 + (L & 15)];
#pragma unroll
    for (int ntc = 0; ntc < 4; ++ntc) {
        f32x4 q1 = {0.f, 0.f, 0.f, 0.f}, q2 = {0.f, 0.f, 0.f, 0.f};
#pragma unroll
        for (int kt = 0; kt < KT; ++kt) {
            int f = kt * 8 + 4 + ntc;
            short8 bh = *(const short8*)(ws + off + f * 1024 + L * 8);
            short8 bl = *(const short8*)(ws + off + f * 1024 + 512 + L * 8);
            q1 = mfma1(Ah[kt], bh, q1);
            q2 = mfma1(Ah[kt], bl, q2);
            q2 = mfma1(Al[kt], bh, q2);
        }
        f32x4 p1 = {0.f, 0.f, 0.f, 0.f}, p2 = {0.f, 0.f, 0.f, 0.f};
#pragma unroll
        for (int kt = 0; kt < KT; ++kt) {
            int f = kt * 8 + ntc;
            short8 bh = *(const short8*)(ws + off + f * 1024 + L * 8);
            short8 bl = *(const short8*)(ws + off + f * 1024 + 512 + L * 8);
            p1 = mfma1(Ah[kt], bh, p1);
            p2 = mfma1(Ah[kt], bl, p2);
            p2 = mfma1(Al[kt], bh, p2);
        }
#pragma unroll
        for (int rr = 0; rr < 4; ++rr) {   // row=(L>>4)*4+rr, col=ntc*16+(L&15)
            int boff = ((L >> 4) * 4 + rr) * PQS + (ntc * 16 + (L & 15)) * 4;
            float q = q1[rr] + q2[rr];
            *(float*)(PQ + QOFF + boff) = q;
            *(float*)(PQ + boff) = p1[rr] + p2[rr] + vbs[ntc] - q;
        }
    }
}
// pack pair (a,b) -> hi u32 [hi(a)|hi(b)] and lo u32 [lo(a)|lo(b)]
__device__ __forceinline__ void pack2(float a, float b, u32& H, u32& Lo) {
    u32 ua = __float_as_uint(a), ub = __float_as_uint(b);
    H = __builtin_amdgcn_perm(ub, ua, 0x07060302);
    float da = a - __uint_as_float(ua & 0xffff0000u);
    float db = b - __uint_as_float(ub & 0xffff0000u);
    u32 r;
    asm("v_cvt_pk_bf16_f32 %0, %1, %2" : "=v"(r) : "v"(da), "v"(db));
    Lo = r;
}
// build one 16x32 A-frag (hi+lo) for this lane from 8-feature plane slices.
__device__ __forceinline__ void buildA1(const char* bp, const char* bq,
                                        short8& Ah, short8& Al) {
    f32x4 p0 = *(const f32x4*)bp,  p1 = *(const f32x4*)(bp + 16);
    f32x4 q0 = *(const f32x4*)bq,  q1 = *(const f32x4*)(bq + 16);
    float h0 = fmaxf(p0[0] + q0[0], 0.f), h1 = fmaxf(p0[1] + q0[1], 0.f);
    float h2 = fmaxf(p0[2] + q0[2], 0.f), h3 = fmaxf(p0[3] + q0[3], 0.f);
    float h4 = fmaxf(p1[0] + q1[0], 0.f), h5 = fmaxf(p1[1] + q1[1], 0.f);
    float h6 = fmaxf(p1[2] + q1[2], 0.f), h7 = fmaxf(p1[3] + q1[3], 0.f);
    u32 H0, H1, H2, H3, L0, L1, L2, L3;
    pack2(h0, h1, H0, L0);
    pack2(h2, h3, H1, L1);
    pack2(h4, h5, H2, L2);
    pack2(h6, h7, H3, L3);
    u32x4 Hv = {H0, H1, H2, H3};
    u32x4 Lv = {L0, L1, L2, L3};
    Ah = __builtin_bit_cast(short8, Hv);
    Al = __builtin_bit_cast(short8, Lv);
}
// build both K-halves (features 0-31, 32-63) of chunk c's A-tile for this lane.
// PP row of node (gb,i) = gb*8+i (== ROW); QQ row of node (gb,j) = gb*8+j.
__device__ __forceinline__ void buildA(const char* PQ, int c, int L,
                                       short8& Ah0, short8& Al0,
                                       short8& Ah1, short8& Al1) {
    int e  = c * 16 + (L & 15);
    int gb = (e >= 42) ? 1 : 0;
    int el = e - gb * 42;               // rows with e>=84 give i=7,8 -> reads
    int i  = el / 6;                    // land in junk/early rows (in-bounds
    int jj = el - i * 6;                // garbage; outputs discarded)
    int j  = jj + (jj >= i);
    const char* bp = PQ + (gb * 8 + i) * PQS + (L >> 4) * 32;
    const char* bq = PQ + QOFF + (gb * 8 + j) * PQS + (L >> 4) * 32;
    buildA1(bp,       bq,       Ah0, Al0);
    buildA1(bp + 128, bq + 128, Ah1, Al1);
}
// fold chunk cc's S rows into per-node running max (column L)
__device__ __forceinline__ void maxread(const char* Sb, int cc, float* mx, int L) {
#pragma unroll
    for (int r = 0; r < 16; ++r) {
        int e = cc * 16 + r;
        if (e < 84) {
            int gb = (e >= 42) ? 1 : 0;
            int i = (e - gb * 42) / 6;
            float sv = *(const float*)(Sb + r * SSTR + L * 4);
            mx[gb * 7 + i] = fmaxf(mx[gb * 7 + i], sv);
        }
    }
}

// EdgeConv second linear (64->64) + max-agg + bias + relu via MFMA.
// A-frags built per chunk directly from PP/QQ. B-frags reloaded per (chunk,nt)
// from ws (L1-resident). Output X written into W (fused).
__device__ __forceinline__ void edgeconv_pipe(const u16* __restrict__ ws, int offB,
                                              char* W, char* Sb, float vb, int L) {
    const char* PQ = W;
    float mx[14];
#pragma unroll
    for (int k = 0; k < 14; ++k) mx[k] = -3.0e38f;
    short8 Ah0, Ah1, Al0, Al1;
    buildA(PQ, 0, L, Ah0, Al0, Ah1, Al1);
#pragma unroll
    for (int c = 0; c < 6; ++c) {
        if (c > 0) maxread(Sb, c - 1, mx, L);      // before S is overwritten
#pragma unroll
        for (int nt = 0; nt < 4; ++nt) {
            short8 bh0 = *(const short8*)(ws + offB + nt * 1024 + L * 8);
            short8 bl0 = *(const short8*)(ws + offB + nt * 1024 + 512 + L * 8);
            short8 bh1 = *(const short8*)(ws + offB + (4 + nt) * 1024 + L * 8);
            short8 bl1 = *(const short8*)(ws + offB + (4 + nt) * 1024 + 512 + L * 8);
            f32x4 a1 = {0.f, 0.f, 0.f, 0.f}, a2 = {0.f, 0.f, 0.f, 0.f};
            a1 = mfma1(Ah0, bh0, a1);
            a2 = mfma1(Ah0, bl0, a2);
            a2 = mfma1(Al0, bh0, a2);
            a1 = mfma1(Ah1, bh1, a1);
            a2 = mfma1(Ah1, bl1, a2);
            a2 = mfma1(Al1, bh1, a2);
#pragma unroll
            for (int rr = 0; rr < 4; ++rr)
                *(float*)(Sb + ((L >> 4) * 4 + rr) * SSTR + nt * 64 + (L & 15) * 4) = a1[rr] + a2[rr];
        }
        if (c < 5) buildA(PQ, c + 1, L, Ah0, Al0, Ah1, Al1);
    }
    maxread(Sb, 5, mx, L);
#pragma unroll
    for (int k = 0; k < 14; ++k)       // fused epilogue (overwrites PP rows; dead)
        putX(W, k, L, fmaxf(mx[k] + vb, 0.f));
}

__global__ __launch_bounds__(128, 3) void gnn_kernel(
    const float* __restrict__ omega, const float* __restrict__ tt, const float* __restrict__ Wf,
    const float* __restrict__ wi1, const float* __restrict__ bi1, const float* __restrict__ bi2,
    const float* __restrict__ bt,
    const float* __restrict__ b1a, const float* __restrict__ b1b,
    const float* __restrict__ b2a, const float* __restrict__ b2b,
    const float* __restrict__ b3a, const float* __restrict__ b3b,
    const u16* __restrict__ ws, float* __restrict__ out)
{
    __shared__ __align__(16) char smem[2 * WREG];   // 25856 B/block
    const int L   = threadIdx.x & 63;
    const int wav = threadIdx.x >> 6;
    const int p   = blockIdx.x * 2 + wav;    // graph pair id, grid covers 25000
    const int g0  = p * 2;
    const int base0 = g0 * 7;                // g1 nodes start at base0+7
    char* W   = smem + wav * WREG;
    char* Sb  = W + SOFF;

    // prefetch h1 inputs (only 5 scalars live across the embedding section)
    float omv = (L < 42) ? omega[base0 * 3 + L] : 0.f;
    float vwi10 = wi1[L], vwi11 = wi1[64 + L], vwi12 = wi1[128 + L];
    float vbi1 = bi1[L];

    // ---- time embedding FIRST (tile-bug: node n uses t[n % B]) ----
    // E staged in W (bf16 planes, cols 0-31); C -> Sb; xs staged back through W
    // once, then its A-frags (kt=2, constant all kernel) held in registers.
    short8 Ah2, Al2;
    {
        int cc = L & 31;
        float vwf = Wf[cc & 15] * 6.283185307179586f;
        int tb = base0 - (base0 / NB) * NB;        // base0 % NB
#pragma unroll
        for (int k = 0; k < 14; ++k) {
            int ti = tb + k; if (ti >= NB) ti -= NB;
            float pj = tt[ti] * vwf;
            float remb = fmaxf((cc < 16) ? __sinf(pj) : __cosf(pj), 0.f);
            u16 h, l;
            split2(remb, h, l);
            if (L < 32) *(u16*)(W + ROW(k) * HSTR + cc * 2) = h;
            else *(u16*)(W + HLO + ROW(k) * HSTR + cc * 2) = l;
        }
        short8 Eh = *(const short8*)(W + (L & 15) * HSTR + (L >> 4) * 16);
        short8 El = *(const short8*)(W + HLO + (L & 15) * HSTR + (L >> 4) * 16);
#pragma unroll
        for (int nt = 0; nt < 2; ++nt) {
            short8 bh = *(const short8*)(ws + OFF_WT + nt * 1024 + L * 8);
            short8 bl = *(const short8*)(ws + OFF_WT + nt * 1024 + 512 + L * 8);
            f32x4 acc = {0.f, 0.f, 0.f, 0.f};
            acc = mfma3(Eh, El, bh, bl, acc);
#pragma unroll
            for (int rr = 0; rr < 4; ++rr)
                *(float*)(Sb + ((L >> 4) * 4 + rr) * SSTR + nt * 64 + (L & 15) * 4) = acc[rr];
        }
        float vbt = bt[cc];
#pragma unroll
        for (int k = 0; k < 14; ++k) {
            float xv = fmaxf(*(const float*)(Sb + ROW(k) * SSTR + cc * 4) + vbt, 0.f);
            u16 h, l;
            split2(xv, h, l);
            if (L < 32) *(u16*)(W + ROW(k) * HSTR + cc * 2) = h;
            else *(u16*)(W + HLO + ROW(k) * HSTR + cc * 2) = l;
        }
        // xs A-frag (cols 0-31 of W == k 64..95), resident for L2a/L3a
        Ah2 = *(const short8*)(W + (L & 15) * HSTR + (L >> 4) * 16);
        Al2 = *(const short8*)(W + HLO + (L & 15) * HSTR + (L >> 4) * 16);
    }

    short8 Ah[3], Al[3];

    // ---- h1 = relu(omega@wi1 + bi1): fused compute -> X (no h1[] array) ----
#pragma unroll
    for (int k = 0; k < 14; ++k) {
        float a0 = bcast(omv, 3 * k), a1 = bcast(omv, 3 * k + 1), a2 = bcast(omv, 3 * k + 2);
        putX(W, k, L, fmaxf(fmaf(a0, vwi10, fmaf(a1, vwi11, fmaf(a2, vwi12, vbi1))), 0.f));
    }

    // ---- init: x0 = h1 @ wi2 + bi2, C written DIRECTLY to X planes ----
    loadA2(W, L, Ah, Al);
    {
        float vbs[4];
#pragma unroll
        for (int ntc = 0; ntc < 4; ++ntc) vbs[ntc] = bi2[ntc * 16 + (L & 15)];
#pragma unroll
        for (int ntc = 0; ntc < 4; ++ntc) {
            f32x4 a1 = {0.f, 0.f, 0.f, 0.f}, a2 = {0.f, 0.f, 0.f, 0.f};
#pragma unroll
            for (int kt = 0; kt < 2; ++kt) {
                int f = kt * 4 + ntc;
                short8 bh = *(const short8*)(ws + OFF_I + f * 1024 + L * 8);
                short8 bl = *(const short8*)(ws + OFF_I + f * 1024 + 512 + L * 8);
                a1 = mfma1(Ah[kt], bh, a1);
                a2 = mfma1(Ah[kt], bl, a2);
                a2 = mfma1(Al[kt], bh, a2);
            }
#pragma unroll
            for (int rr = 0; rr < 4; ++rr) {   // row=(L>>4)*4+rr, col=ntc*16+(L&15)
                int r = (L >> 4) * 4 + rr;
                int col = ntc * 16 + (L & 15);
                u16 h, l;
                split2(a1[rr] + a2[rr] + vbs[ntc], h, l);
                *(u16*)(W + r * HSTR + col * 2) = h;
                *(u16*)(W + HLO + r * HSTR + col * 2) = l;
            }
        }
    }

    // ---- L1a (K=64): fused qq+pp, direct PP/QQ writes ----
    loadA2(W, L, Ah, Al);
    layer_pass<2>(ws, OFF_1A, Ah, Al, W, b1a, L);
    // ---- L1b (X out -> W) ----
    edgeconv_pipe(ws, OFF_1B, W, Sb, b1b[L], L);

    // ---- L2a (K=96: [x | xs]) ----
    loadA2(W, L, Ah, Al);
    Ah[2] = Ah2; Al[2] = Al2;
    layer_pass<3>(ws, OFF_2A, Ah, Al, W, b2a, L);
    // ---- L2b ----
    edgeconv_pipe(ws, OFF_2B, W, Sb, b2b[L], L);

    // ---- L3a (K=96) ----
    loadA2(W, L, Ah, Al);
    Ah[2] = Ah2; Al[2] = Al2;
    layer_pass<3>(ws, OFF_3A, Ah, Al, W, b3a, L);

    // ---- L3b (64->3) via MFMA + max + /(std+1e-7) ----
    {
        const char* PQ = W;
        short8 B0h = *(const short8*)(ws + OFF_3B + L * 8);
        short8 B0l = *(const short8*)(ws + OFF_3B + 512 + L * 8);
        short8 B1h = *(const short8*)(ws + OFF_3B + 1024 + L * 8);
        short8 B1l = *(const short8*)(ws + OFF_3B + 1536 + L * 8);
        short8 Ah0, Ah1, Al0, Al1;
        buildA(PQ, 0, L, Ah0, Al0, Ah1, Al1);
#pragma unroll
        for (int c = 0; c < 6; ++c) {
            f32x4 a1 = {0.f, 0.f, 0.f, 0.f}, a2 = {0.f, 0.f, 0.f, 0.f};
            a1 = mfma1(Ah0, B0h, a1);
            a2 = mfma1(Ah0, B0l, a2);
            a2 = mfma1(Al0, B0h, a2);
            a1 = mfma1(Ah1, B1h, a1);
            a2 = mfma1(Ah1, B1l, a2);
            a2 = mfma1(Al1, B1h, a2);
            if ((L & 15) < 3) {       // compact strip: row e (96), stride 16B, col 0..2
#pragma unroll
                for (int rr = 0; rr < 4; ++rr)
                    *(float*)(Sb + (c * 16 + (L >> 4) * 4 + rr) * 16 + (L & 15) * 4) = a1[rr] + a2[rr];
            }
            if (c < 5) buildA(PQ, c + 1, L, Ah0, Al0, Ah1, Al1);
        }
        if (L < 42) {                 // lanes 0-20: g0; 21-41: g1
            int gb = (L >= 21) ? 1 : 0;
            int ll = L - gb * 21;
            int i = ll / 3, col = ll - i * 3;
            int e0 = gb * 42 + i * 6;
            float m = -3.0e38f;
#pragma unroll
            for (int e6 = 0; e6 < 6; ++e6)
                m = fmaxf(m, *(const float*)(Sb + (e0 + e6) * 16 + col * 4));
            m += b3b[col];
            float tg = tt[g0 + gb];   // std uses t[n // 7]
            float stdv = sqrtf((exp2f(tg * 9.287712379549448f) - 1.0f) * 0.15533740282828987f);
            out[base0 * 3 + L] = m / (stdv + 1e-7f);   // contiguous 42 outputs
        }
    }
}

extern "C" void kernel_launch(void* const* d_in, const int* in_sizes, int n_in,
                              void* d_out, int out_size, void* d_ws, size_t ws_size,
                              hipStream_t stream) {
    const float* omega = (const float*)d_in[0];
    // d_in[1] edge_index unused (fixed fully-connected); d_in[3] num_objs == 7
    const float* tt  = (const float*)d_in[2];
    const float* Wf  = (const float*)d_in[4];
    const float* wi1 = (const float*)d_in[5];
    const float* bi1 = (const float*)d_in[6];
    const float* wi2 = (const float*)d_in[7];
    const float* bi2 = (const float*)d_in[8];
    const float* wt  = (const float*)d_in[9];
    const float* bt  = (const float*)d_in[10];
    const float* w1a = (const float*)d_in[11];
    const float* b1a = (const float*)d_in[12];
    const float* w1b = (const float*)d_in[13];
    const float* b1b = (const float*)d_in[14];
    const float* w2a = (const float*)d_in[15];
    const float* b2a = (const float*)d_in[16];
    const float* w2b = (const float*)d_in[17];
    const float* b2b = (const float*)d_in[18];
    const float* w3a = (const float*)d_in[19];
    const float* b3a = (const float*)d_in[20];
    const float* w3b = (const float*)d_in[21];
    const float* b3b = (const float*)d_in[22];
    u16* ws = (u16*)d_ws;   // needs 188416 bytes

    pack_kernel<<<dim3(92, 8), dim3(128), 0, stream>>>(wi2, w1a, w2a, w3a, w1b, w2b, wt, w3b, ws);
    gnn_kernel<<<dim3(12500), dim3(128), 0, stream>>>(
        omega, tt, Wf, wi1, bi1, bi2, bt,
        b1a, b1b, b2a, b2b, b3a, b3b, ws, (float*)d_out);
}

// Round 13
// 394.533 us; speedup vs baseline: 1.0657x; 1.0657x over previous
//
#include <hip/hip_runtime.h>

// ScoreNetGNN: B=50000 graphs x 7 nodes, fully-connected (42 edges/graph).
// R6: MFMA pipeline (16x16x32 bf16 split hi+lo). R12: truncation-split.
// R13: parallel pack + packed-H. R16: B-frags from L1 + (128,3): occ 31.4%.
// R17: H staging killed; A-frags built from PQ LDS. R19/R24: liveness
//   surgery -> VERIFIED BEST (counter 333+-4us; bench 396-406 band).
// All later structural variants regressed and are reverted:
//   R20 AGPR parking -10% (accvgpr moves around MFMA; spill was benign).
//   R21 packed-X staging: neutral (DS savings off critical path).
//   R22 in-register max-agg -11% (serial swizzle/bpermute after MFMA).
//   R23 setprio + B-preload -7% (perturbs compiler MFMA schedule).
//   R25 fused layer_pass -8% (q-regs live across pp cluster -> +70MB spill
//       INSIDE the hot path; FETCH 21->83MB, MfmaUtil 31->28).
// Plateau characterization (R13-R25): total reg allocation = 2x arch VGPR
//   (4/4 configs exact) -> hard 3 waves/SIMD cap at arch 84; at that
//   occupancy the kernel is latency/issue-limited (VALU 52%, MFMA 31%,
//   HBM 0.3%); six pipe-shifting attempts all lost on the critical path.
//   This decomposition's optimum is this kernel.
// f32 I/O hardcoded (R3 counters: WRITE_SIZE = 4 B/elem).

#define NB 50000

typedef unsigned short u16;
typedef unsigned int u32;
typedef short short8 __attribute__((ext_vector_type(8)));
typedef float f32x4 __attribute__((ext_vector_type(4)));
typedef unsigned int u32x4 __attribute__((ext_vector_type(4)));

// d_ws fragment offsets (u16 units). frag stride 1024 u16 (hi 512 | lo 512),
// lane entry = 8 u16 (16B). Total 94208 u16 = 188416 bytes.
#define OFF_I  0
#define OFF_1A 8192
#define OFF_2A 24576
#define OFF_3A 49152
#define OFF_1B 73728
#define OFF_2B 81920
#define OFF_WT 90112
#define OFF_3B 92160

// LDS per-wave geometry (bytes), base W:
//  [0,4608)     X: 16 rows x 64 bf16 @ stride 144, hi [0,2304) lo [2304,4608)
//  [0,8512)     PQ: 28 rows x 64 f32 @ stride 304 (rows 0-13 pp', 14-27 qq).
//               Overlays X; uses are time-disjoint.
//  [8512,12736) Sb: f32 C 16 rows @ stride 264
#define HSTR 144
#define HLO  2304
#define PQS  304
#define SOFF 8512
#define SSTR 264
#define WREG 12736

__device__ __forceinline__ float b2f(u16 u) {
    return __uint_as_float(((u32)u) << 16);
}
__device__ __forceinline__ u16 f2b(float f) {
    u32 u = __float_as_uint(f);
    u += 0x7FFFu + ((u >> 16) & 1u);   // RNE
    return (u16)(u >> 16);
}
// split v into bf16 hi (truncated, v-hi exact) + bf16 lo (RNE of residual)
__device__ __forceinline__ void split2(float v, u16& h, u16& l) {
    u32 u = __float_as_uint(v);
    h = (u16)(u >> 16);
    float d = v - __uint_as_float(u & 0xffff0000u);
    l = f2b(d);
}
__device__ __forceinline__ float bcast(float v, int l) {
    return __uint_as_float(__builtin_amdgcn_readlane(__float_as_uint(v), l));
}

// ---- setup: pack weights into split-bf16 MFMA B-fragments ----
// grid (92, 8): blockIdx.y = element j within lane entry; 128 thr = half x lane.
__global__ __launch_bounds__(128) void pack_kernel(
    const float* __restrict__ wi2, const float* __restrict__ w1a,
    const float* __restrict__ w2a, const float* __restrict__ w3a,
    const float* __restrict__ w1b, const float* __restrict__ w2b,
    const float* __restrict__ wt,  const float* __restrict__ w3b,
    u16* __restrict__ ws)
{
    int blk = blockIdx.x;
    int j    = blockIdx.y;
    int half = threadIdx.x >> 6;          // 0 = hi, 1 = lo
    int lane = threadIdx.x & 63;
    float v;
    u16* dst;
    if (blk < 88) {
        const float* src; int NT, qoff, obase, frag;
        if (blk < 8)       { src = wi2; NT = 4; qoff = 0;  obase = OFF_I;  frag = blk;      }
        else if (blk < 24) { src = w1a; NT = 8; qoff = 64; obase = OFF_1A; frag = blk - 8;  }
        else if (blk < 48) { src = w2a; NT = 8; qoff = 96; obase = OFF_2A; frag = blk - 24; }
        else if (blk < 72) { src = w3a; NT = 8; qoff = 96; obase = OFF_3A; frag = blk - 48; }
        else if (blk < 80) { src = w1b; NT = 4; qoff = 0;  obase = OFF_1B; frag = blk - 72; }
        else               { src = w2b; NT = 4; qoff = 0;  obase = OFF_2B; frag = blk - 80; }
        int kt = frag / NT, nt = frag % NT;
        int k = kt * 32 + (lane >> 4) * 8 + j;
        int n = nt * 16 + (lane & 15);
        int idx = (n < 64) ? (k * 64 + n) : ((qoff + k) * 64 + (n - 64));
        v = src[idx];
        dst = ws + obase + frag * 1024 + half * 512 + lane * 8 + j;
    } else if (blk < 90) {               // wt (32,32): 2 n-frags
        int frag = blk - 88;
        int k = (lane >> 4) * 8 + j;
        int n = frag * 16 + (lane & 15);
        v = wt[k * 32 + n];
        dst = ws + OFF_WT + frag * 1024 + half * 512 + lane * 8 + j;
    } else {                             // w3b (64,3): 2 k-frags, cols 3..15 = 0
        int frag = blk - 90;
        int k = frag * 32 + (lane >> 4) * 8 + j;
        int n = lane & 15;
        v = (n < 3) ? w3b[k * 3 + n] : 0.f;
        dst = ws + OFF_3B + frag * 1024 + half * 512 + lane * 8 + j;
    }
    u16 hi = f2b(v);
    *dst = (half == 0) ? hi : f2b(v - b2f(hi));
}

__device__ __forceinline__ f32x4 mfma1(short8 a, short8 b, f32x4 acc) {
    return __builtin_amdgcn_mfma_f32_16x16x32_bf16(a, b, acc, 0, 0, 0);
}
__device__ __forceinline__ f32x4 mfma3(short8 ah, short8 al, short8 bh, short8 bl, f32x4 acc) {
    acc = mfma1(ah, bh, acc);
    acc = mfma1(ah, bl, acc);
    acc = mfma1(al, bh, acc);
    return acc;   // lo*lo dropped
}

// node k (0..13) -> row (g0 rows 0-6, g1 rows 8-14; rows 7,15 stale/unread)
#define ROW(k) ((k) < 7 ? (k) : (k) + 1)

// write one node value (col L) into X planes of region G
__device__ __forceinline__ void putX(char* G, int k, int L, float v) {
    int r = ROW(k);
    u16 h, l;
    split2(v, h, l);
    *(u16*)(G + r * HSTR + L * 2) = h;
    *(u16*)(G + HLO + r * HSTR + L * 2) = l;
}
// A-frags kt 0,1 from G (cols 0-63); kt 2 (xs) is register-resident.
__device__ __forceinline__ void loadA2(const char* G, int L, short8* Ah, short8* Al) {
#pragma unroll
    for (int kt = 0; kt < 2; ++kt) {
        Ah[kt] = *(const short8*)(G + (L & 15) * HSTR + kt * 64 + (L >> 4) * 16);
        Al[kt] = *(const short8*)(G + HLO + (L & 15) * HSTR + kt * 64 + (L >> 4) * 16);
    }
}
// One 4-N-tile GEMM pass: S[row][col 0..63] = A(16xK) @ B(Kx64).
template<int KT, int NT>
__device__ __forceinline__ void lin_pass(const u16* __restrict__ ws, int off, int nt0,
                                         const short8* Ah, const short8* Al,
                                         char* Sg, int L) {
#pragma unroll
    for (int ntc = 0; ntc < 4; ++ntc) {
        f32x4 a1 = {0.f, 0.f, 0.f, 0.f}, a2 = {0.f, 0.f, 0.f, 0.f};
#pragma unroll
        for (int kt = 0; kt < KT; ++kt) {
            int f = kt * NT + nt0 + ntc;
            short8 bh = *(const short8*)(ws + off + f * 1024 + L * 8);
            short8 bl = *(const short8*)(ws + off + f * 1024 + 512 + L * 8);
            a1 = mfma1(Ah[kt], bh, a1);
            a2 = mfma1(Ah[kt], bl, a2);
            a2 = mfma1(Al[kt], bh, a2);
        }
#pragma unroll
        for (int rr = 0; rr < 4; ++rr)   // C: row=(L>>4)*4+rr, col=ntc*16+(L&15)
            *(float*)(Sg + ((L >> 4) * 4 + rr) * SSTR + ntc * 64 + (L & 15) * 4) = a1[rr] + a2[rr];
    }
}
// copy qq half (Sb rows) -> PQ rows 14..27 (one temp, no register array)
__device__ __forceinline__ void copyQ(char* PQ, const char* Sb, int L) {
#pragma unroll
    for (int k = 0; k < 14; ++k)
        *(float*)(PQ + (14 + k) * PQS + L * 4) =
            *(const float*)(Sb + ROW(k) * SSTR + L * 4);
}
// pp fixup: PQ row k = Sb_pp[k] + vb - qq[k]  (qq read back from PQ)
__device__ __forceinline__ void fixP(char* PQ, const char* Sb, float vb, int L) {
#pragma unroll
    for (int k = 0; k < 14; ++k) {
        float p = *(const float*)(Sb + ROW(k) * SSTR + L * 4);
        float q = *(const float*)(PQ + (14 + k) * PQS + L * 4);
        *(float*)(PQ + k * PQS + L * 4) = p + vb - q;
    }
}
// pack pair (a,b) -> hi u32 [hi(a)|hi(b)] and lo u32 [lo(a)|lo(b)]
__device__ __forceinline__ void pack2(float a, float b, u32& H, u32& Lo) {
    u32 ua = __float_as_uint(a), ub = __float_as_uint(b);
    H = __builtin_amdgcn_perm(ub, ua, 0x07060302);
    float da = a - __uint_as_float(ua & 0xffff0000u);
    float db = b - __uint_as_float(ub & 0xffff0000u);
    u32 r;
    asm("v_cvt_pk_bf16_f32 %0, %1, %2" : "=v"(r) : "v"(da), "v"(db));
    Lo = r;
}
// build one 16x32 A-frag (hi+lo) for this lane from 8-feature PQ slices.
__device__ __forceinline__ void buildA1(const char* bp, const char* bq,
                                        short8& Ah, short8& Al) {
    f32x4 p0 = *(const f32x4*)bp,  p1 = *(const f32x4*)(bp + 16);
    f32x4 q0 = *(const f32x4*)bq,  q1 = *(const f32x4*)(bq + 16);
    float h0 = fmaxf(p0[0] + q0[0], 0.f), h1 = fmaxf(p0[1] + q0[1], 0.f);
    float h2 = fmaxf(p0[2] + q0[2], 0.f), h3 = fmaxf(p0[3] + q0[3], 0.f);
    float h4 = fmaxf(p1[0] + q1[0], 0.f), h5 = fmaxf(p1[1] + q1[1], 0.f);
    float h6 = fmaxf(p1[2] + q1[2], 0.f), h7 = fmaxf(p1[3] + q1[3], 0.f);
    u32 H0, H1, H2, H3, L0, L1, L2, L3;
    pack2(h0, h1, H0, L0);
    pack2(h2, h3, H1, L1);
    pack2(h4, h5, H2, L2);
    pack2(h6, h7, H3, L3);
    u32x4 Hv = {H0, H1, H2, H3};
    u32x4 Lv = {L0, L1, L2, L3};
    Ah = __builtin_bit_cast(short8, Hv);
    Al = __builtin_bit_cast(short8, Lv);
}
// build both K-halves (features 0-31, 32-63) of chunk c's A-tile for this lane
__device__ __forceinline__ void buildA(const char* PQ, int c, int L,
                                       short8& Ah0, short8& Al0,
                                       short8& Ah1, short8& Al1) {
    int e  = c * 16 + (L & 15);
    int gb = (e >= 42) ? 1 : 0;
    int el = e - gb * 42;               // rows with e>=84 give i=7,8 -> reads
    int i  = el / 6;                    // land in qq rows 14,15 (in-bounds
    int jj = el - i * 6;                // garbage; outputs discarded)
    int j  = jj + (jj >= i);
    const char* bp = PQ + (gb * 7 + i) * PQS + (L >> 4) * 32;
    const char* bq = PQ + (14 + gb * 7 + j) * PQS + (L >> 4) * 32;
    buildA1(bp,       bq,       Ah0, Al0);
    buildA1(bp + 128, bq + 128, Ah1, Al1);
}
// fold chunk cc's S rows into per-node running max (column L)
__device__ __forceinline__ void maxread(const char* Sb, int cc, float* mx, int L) {
#pragma unroll
    for (int r = 0; r < 16; ++r) {
        int e = cc * 16 + r;
        if (e < 84) {
            int gb = (e >= 42) ? 1 : 0;
            int i = (e - gb * 42) / 6;
            float sv = *(const float*)(Sb + r * SSTR + L * 4);
            mx[gb * 7 + i] = fmaxf(mx[gb * 7 + i], sv);
        }
    }
}

// EdgeConv second linear (64->64) + max-agg + bias + relu via MFMA.
// A-frags built per chunk directly from PQ (no H staging). B-frags reloaded
// per (chunk,nt) from ws (L1-resident). Output X written into W (fused).
__device__ __forceinline__ void edgeconv_pipe(const u16* __restrict__ ws, int offB,
                                              char* W, char* Sb, float vb, int L) {
    const char* PQ = W;
    float mx[14];
#pragma unroll
    for (int k = 0; k < 14; ++k) mx[k] = -3.0e38f;
    short8 Ah0, Ah1, Al0, Al1;
    buildA(PQ, 0, L, Ah0, Al0, Ah1, Al1);
#pragma unroll
    for (int c = 0; c < 6; ++c) {
        if (c > 0) maxread(Sb, c - 1, mx, L);      // before S is overwritten
#pragma unroll
        for (int nt = 0; nt < 4; ++nt) {
            short8 bh0 = *(const short8*)(ws + offB + nt * 1024 + L * 8);
            short8 bl0 = *(const short8*)(ws + offB + nt * 1024 + 512 + L * 8);
            short8 bh1 = *(const short8*)(ws + offB + (4 + nt) * 1024 + L * 8);
            short8 bl1 = *(const short8*)(ws + offB + (4 + nt) * 1024 + 512 + L * 8);
            f32x4 a1 = {0.f, 0.f, 0.f, 0.f}, a2 = {0.f, 0.f, 0.f, 0.f};
            a1 = mfma1(Ah0, bh0, a1);
            a2 = mfma1(Ah0, bl0, a2);
            a2 = mfma1(Al0, bh0, a2);
            a1 = mfma1(Ah1, bh1, a1);
            a2 = mfma1(Ah1, bl1, a2);
            a2 = mfma1(Al1, bh1, a2);
#pragma unroll
            for (int rr = 0; rr < 4; ++rr)
                *(float*)(Sb + ((L >> 4) * 4 + rr) * SSTR + nt * 64 + (L & 15) * 4) = a1[rr] + a2[rr];
        }
        if (c < 5) buildA(PQ, c + 1, L, Ah0, Al0, Ah1, Al1);
    }
    maxread(Sb, 5, mx, L);
#pragma unroll
    for (int k = 0; k < 14; ++k)       // fused epilogue (overwrites PQ rows 0-15)
        putX(W, k, L, fmaxf(mx[k] + vb, 0.f));
}

__global__ __launch_bounds__(128, 3) void gnn_kernel(
    const float* __restrict__ omega, const float* __restrict__ tt, const float* __restrict__ Wf,
    const float* __restrict__ wi1, const float* __restrict__ bi1, const float* __restrict__ bi2,
    const float* __restrict__ bt,
    const float* __restrict__ b1a, const float* __restrict__ b1b,
    const float* __restrict__ b2a, const float* __restrict__ b2b,
    const float* __restrict__ b3a, const float* __restrict__ b3b,
    const u16* __restrict__ ws, float* __restrict__ out)
{
    __shared__ __align__(16) char smem[2 * WREG];   // 25472 B/block
    const int L   = threadIdx.x & 63;
    const int wav = threadIdx.x >> 6;
    const int p   = blockIdx.x * 2 + wav;    // graph pair id, grid covers 25000
    const int g0  = p * 2;
    const int base0 = g0 * 7;                // g1 nodes start at base0+7
    char* W   = smem + wav * WREG;
    char* Sb  = W + SOFF;

    // prefetch h1 inputs (only 5 scalars live across the embedding section)
    float omv = (L < 42) ? omega[base0 * 3 + L] : 0.f;
    float vwi10 = wi1[L], vwi11 = wi1[64 + L], vwi12 = wi1[128 + L];
    float vbi1 = bi1[L];

    // ---- time embedding FIRST (tile-bug: node n uses t[n % B]) ----
    // E staged in W (bf16 planes, cols 0-31); C -> Sb; xs staged back through W
    // once, then its A-frags (kt=2, constant all kernel) held in registers.
    short8 Ah2, Al2;
    {
        int cc = L & 31;
        float vwf = Wf[cc & 15] * 6.283185307179586f;
        int tb = base0 - (base0 / NB) * NB;        // base0 % NB
#pragma unroll
        for (int k = 0; k < 14; ++k) {
            int ti = tb + k; if (ti >= NB) ti -= NB;
            float pj = tt[ti] * vwf;
            float remb = fmaxf((cc < 16) ? __sinf(pj) : __cosf(pj), 0.f);
            u16 h, l;
            split2(remb, h, l);
            if (L < 32) *(u16*)(W + ROW(k) * HSTR + cc * 2) = h;
            else *(u16*)(W + HLO + ROW(k) * HSTR + cc * 2) = l;
        }
        short8 Eh = *(const short8*)(W + (L & 15) * HSTR + (L >> 4) * 16);
        short8 El = *(const short8*)(W + HLO + (L & 15) * HSTR + (L >> 4) * 16);
#pragma unroll
        for (int nt = 0; nt < 2; ++nt) {
            short8 bh = *(const short8*)(ws + OFF_WT + nt * 1024 + L * 8);
            short8 bl = *(const short8*)(ws + OFF_WT + nt * 1024 + 512 + L * 8);
            f32x4 acc = {0.f, 0.f, 0.f, 0.f};
            acc = mfma3(Eh, El, bh, bl, acc);
#pragma unroll
            for (int rr = 0; rr < 4; ++rr)
                *(float*)(Sb + ((L >> 4) * 4 + rr) * SSTR + nt * 64 + (L & 15) * 4) = acc[rr];
        }
        float vbt = bt[cc];
#pragma unroll
        for (int k = 0; k < 14; ++k) {
            float xv = fmaxf(*(const float*)(Sb + ROW(k) * SSTR + cc * 4) + vbt, 0.f);
            u16 h, l;
            split2(xv, h, l);
            if (L < 32) *(u16*)(W + ROW(k) * HSTR + cc * 2) = h;
            else *(u16*)(W + HLO + ROW(k) * HSTR + cc * 2) = l;
        }
        // xs A-frag (cols 0-31 of W == k 64..95), resident for L2a/L3a
        Ah2 = *(const short8*)(W + (L & 15) * HSTR + (L >> 4) * 16);
        Al2 = *(const short8*)(W + HLO + (L & 15) * HSTR + (L >> 4) * 16);
    }

    short8 Ah[3], Al[3];

    // ---- h1 = relu(omega@wi1 + bi1): fused compute -> X (no h1[] array) ----
#pragma unroll
    for (int k = 0; k < 14; ++k) {
        float a0 = bcast(omv, 3 * k), a1 = bcast(omv, 3 * k + 1), a2 = bcast(omv, 3 * k + 2);
        putX(W, k, L, fmaxf(fmaf(a0, vwi10, fmaf(a1, vwi11, fmaf(a2, vwi12, vbi1))), 0.f));
    }

    // ---- init: x0 = h1 @ wi2 + bi2 (fused epilogue, no xh[] array) ----
    loadA2(W, L, Ah, Al);
    lin_pass<2, 4>(ws, OFF_I, 0, Ah, Al, Sb, L);
    {
        float vbi2 = bi2[L];
#pragma unroll
        for (int k = 0; k < 14; ++k)
            putX(W, k, L, *(const float*)(Sb + ROW(k) * SSTR + L * 4) + vbi2);
    }

    // ---- L1a (K=64): qq half first, then pp half + LDS fixup ----
    loadA2(W, L, Ah, Al);
    lin_pass<2, 8>(ws, OFF_1A, 4, Ah, Al, Sb, L);
    copyQ(W, Sb, L);
    lin_pass<2, 8>(ws, OFF_1A, 0, Ah, Al, Sb, L);
    fixP(W, Sb, b1a[L], L);
    // ---- L1b (X out -> W) ----
    edgeconv_pipe(ws, OFF_1B, W, Sb, b1b[L], L);

    // ---- L2a (K=96: [x | xs]) ----
    loadA2(W, L, Ah, Al);
    Ah[2] = Ah2; Al[2] = Al2;
    lin_pass<3, 8>(ws, OFF_2A, 4, Ah, Al, Sb, L);
    copyQ(W, Sb, L);
    lin_pass<3, 8>(ws, OFF_2A, 0, Ah, Al, Sb, L);
    fixP(W, Sb, b2a[L], L);
    // ---- L2b ----
    edgeconv_pipe(ws, OFF_2B, W, Sb, b2b[L], L);

    // ---- L3a (K=96) ----
    loadA2(W, L, Ah, Al);
    Ah[2] = Ah2; Al[2] = Al2;
    lin_pass<3, 8>(ws, OFF_3A, 4, Ah, Al, Sb, L);
    copyQ(W, Sb, L);
    lin_pass<3, 8>(ws, OFF_3A, 0, Ah, Al, Sb, L);
    fixP(W, Sb, b3a[L], L);

    // ---- L3b (64->3) via MFMA + max + /(std+1e-7) ----
    {
        const char* PQ = W;
        short8 B0h = *(const short8*)(ws + OFF_3B + L * 8);
        short8 B0l = *(const short8*)(ws + OFF_3B + 512 + L * 8);
        short8 B1h = *(const short8*)(ws + OFF_3B + 1024 + L * 8);
        short8 B1l = *(const short8*)(ws + OFF_3B + 1536 + L * 8);
        short8 Ah0, Ah1, Al0, Al1;
        buildA(PQ, 0, L, Ah0, Al0, Ah1, Al1);
#pragma unroll
        for (int c = 0; c < 6; ++c) {
            f32x4 a1 = {0.f, 0.f, 0.f, 0.f}, a2 = {0.f, 0.f, 0.f, 0.f};
            a1 = mfma1(Ah0, B0h, a1);
            a2 = mfma1(Ah0, B0l, a2);
            a2 = mfma1(Al0, B0h, a2);
            a1 = mfma1(Ah1, B1h, a1);
            a2 = mfma1(Ah1, B1l, a2);
            a2 = mfma1(Al1, B1h, a2);
            if ((L & 15) < 3) {       // compact strip: row e (96), stride 16B, col 0..2
#pragma unroll
                for (int rr = 0; rr < 4; ++rr)
                    *(float*)(Sb + (c * 16 + (L >> 4) * 4 + rr) * 16 + (L & 15) * 4) = a1[rr] + a2[rr];
            }
            if (c < 5) buildA(PQ, c + 1, L, Ah0, Al0, Ah1, Al1);
        }
        if (L < 42) {                 // lanes 0-20: g0; 21-41: g1
            int gb = (L >= 21) ? 1 : 0;
            int ll = L - gb * 21;
            int i = ll / 3, col = ll - i * 3;
            int e0 = gb * 42 + i * 6;
            float m = -3.0e38f;
#pragma unroll
            for (int e6 = 0; e6 < 6; ++e6)
                m = fmaxf(m, *(const float*)(Sb + (e0 + e6) * 16 + col * 4));
            m += b3b[col];
            float tg = tt[g0 + gb];   // std uses t[n // 7]
            float stdv = sqrtf((exp2f(tg * 9.287712379549448f) - 1.0f) * 0.15533740282828987f);
            out[base0 * 3 + L] = m / (stdv + 1e-7f);   // contiguous 42 outputs
        }
    }
}

extern "C" void kernel_launch(void* const* d_in, const int* in_sizes, int n_in,
                              void* d_out, int out_size, void* d_ws, size_t ws_size,
                              hipStream_t stream) {
    const float* omega = (const float*)d_in[0];
    // d_in[1] edge_index unused (fixed fully-connected); d_in[3] num_objs == 7
    const float* tt  = (const float*)d_in[2];
    const float* Wf  = (const float*)d_in[4];
    const float* wi1 = (const float*)d_in[5];
    const float* bi1 = (const float*)d_in[6];
    const float* wi2 = (const float*)d_in[7];
    const float* bi2 = (const float*)d_in[8];
    const float* wt  = (const float*)d_in[9];
    const float* bt  = (const float*)d_in[10];
    const float* w1a = (const float*)d_in[11];
    const float* b1a = (const float*)d_in[12];
    const float* w1b = (const float*)d_in[13];
    const float* b1b = (const float*)d_in[14];
    const float* w2a = (const float*)d_in[15];
    const float* b2a = (const float*)d_in[16];
    const float* w2b = (const float*)d_in[17];
    const float* b2b = (const float*)d_in[18];
    const float* w3a = (const float*)d_in[19];
    const float* b3a = (const float*)d_in[20];
    const float* w3b = (const float*)d_in[21];
    const float* b3b = (const float*)d_in[22];
    u16* ws = (u16*)d_ws;   // needs 188416 bytes

    pack_kernel<<<dim3(92, 8), dim3(128), 0, stream>>>(wi2, w1a, w2a, w3a, w1b, w2b, wt, w3b, ws);
    gnn_kernel<<<dim3(12500), dim3(128), 0, stream>>>(
        omega, tt, Wf, wi1, bi1, bi2, bt,
        b1a, b1b, b2a, b2b, b3a, b3b, ws, (float*)d_out);
}